// Round 12
// baseline (128.019 us; speedup 1.0000x reference)
//
#include <hip/hip_runtime.h>
#include <hip/hip_bf16.h>

#define BATCH 8
#define NDIM  2048
#define MDIM  2048
#define CDIM  128

typedef __attribute__((ext_vector_type(8))) short bf16x8;
typedef __attribute__((ext_vector_type(4))) float f32x4;
// 4B-aligned float4 for the (out+1)-offset misaligned global stores
typedef __attribute__((ext_vector_type(4), aligned(4))) float f32x4u;

__device__ __forceinline__ float bf2f(unsigned int u16){
    union { unsigned int u; float f; } v; v.u = u16 << 16; return v.f;
}
__device__ __forceinline__ unsigned int f2bf(float f){
    union { float f; unsigned int u; } v; v.f = f;
    unsigned int u = v.u;
    u += 0x7FFFu + ((u >> 16) & 1u);   // round-to-nearest-even
    return u >> 16;
}

__device__ __forceinline__ void gload_lds16(const void* g, void* l){
    __builtin_amdgcn_global_load_lds(
        (const __attribute__((address_space(1))) void*)g,
        (__attribute__((address_space(3))) void*)l, 16, 0, 0);
}

__global__ void finalize_kernel(const float* cells, float* out){
    float s = 0.f;
    int   c = 0;
    #pragma unroll
    for (int i = 0; i < 32; ++i){
        s += cells[i];
        c += ((const int*)cells)[32 + i];
    }
    out[0] = s / (float)c;
}

// ---------------- pre-pass: f32 -> bf16 + per-row 1/||row|| + cells zero ----------------
__global__ __launch_bounds__(256) void prep_kernel(
    const float* __restrict__ x1, const float* __restrict__ x2,
    unsigned short* __restrict__ xb, float* __restrict__ inv,
    unsigned int* __restrict__ cells)
{
    if (blockIdx.x == 0 && threadIdx.x < 64) cells[threadIdx.x] = 0u;

    int gt  = blockIdx.x*256 + threadIdx.x;   // 0..524287
    int row = gt >> 4;                        // 0..32767
    int seg = gt & 15;                        // 8-elem segment
    const float* src = (row < 16384) ? (x1 + (size_t)row*128)
                                     : (x2 + (size_t)(row - 16384)*128);
    float4 a = *(const float4*)(src + seg*8);
    float4 b = *(const float4*)(src + seg*8 + 4);
    uint4 pk;
    pk.x = f2bf(a.x) | (f2bf(a.y) << 16);
    pk.y = f2bf(a.z) | (f2bf(a.w) << 16);
    pk.z = f2bf(b.x) | (f2bf(b.y) << 16);
    pk.w = f2bf(b.z) | (f2bf(b.w) << 16);
    ((uint4*)xb)[(size_t)row*16 + seg] = pk;

    float f0 = bf2f(pk.x & 0xffffu), f1 = bf2f(pk.x >> 16);
    float f2 = bf2f(pk.y & 0xffffu), f3 = bf2f(pk.y >> 16);
    float f4 = bf2f(pk.z & 0xffffu), f5 = bf2f(pk.z >> 16);
    float f6 = bf2f(pk.w & 0xffffu), f7 = bf2f(pk.w >> 16);
    float s = f0*f0 + f1*f1 + f2*f2 + f3*f3 + f4*f4 + f5*f5 + f6*f6 + f7*f7;
    s += __shfl_xor(s, 1);
    s += __shfl_xor(s, 2);
    s += __shfl_xor(s, 4);
    s += __shfl_xor(s, 8);
    if (seg == 0) inv[row] = 1.0f / sqrtf(fmaxf(s, 1e-16f));
}

// ---------------- main (R8 structure + full-z-prefetch + exp2 softplus) ----------------
// Tile 64(N) x 128(M); 256 thr / 4 waves; wave owns 16 rows x 128 cols (acc = 32 AGPR).
// B tile [128][128] bf16 (32 KB) staged in ONE global_load_lds round, XOR-swizzle
// folded into the global SOURCE address; z tile FULLY prefetched (8 int4 = 32 VGPR)
// before staging; barrier-free per-wave transpose epilogue (R6-proven store pattern).
// launch_bounds(256,5): 102-reg cap; est. 64 VGPR + 32 AGPR = 96.
__global__ __launch_bounds__(256, 5) void cossim_bce_fast(
    const int*  __restrict__ zp,
    const unsigned short* __restrict__ xb,
    const float* __restrict__ inv,
    const float* __restrict__ tparm,
    const float* __restrict__ bparm,
    float* __restrict__ out,
    float* __restrict__ cells)
{
    __shared__ __align__(16) unsigned short lB[128*128];   // 32 KB; scratch overlay

    const int t  = threadIdx.x;
    const int bx = blockIdx.x;   // M tile 0..15
    const int by = blockIdx.y;   // N tile 0..31
    const int bz = blockIdx.z;   // batch

    // exp2-domain softplus: y2 = z*(t2*cs - b2); nll = ln2 * softplus2(-y2)
    const float t2 = *tparm * 1.44269504f;
    const float b2 = *bparm * 1.44269504f;

    const unsigned short* x1b = xb;                          // 16384 x 128
    const unsigned short* x2b = xb + (size_t)16384*128;      // 16384 x 128
    const int x2r0 = bz*MDIM + bx*128;

    const int lane = t & 63;
    const int w    = t >> 6;
    const int quad = lane >> 4;      // 0..3
    const int l16  = lane & 15;
    const int hi   = lane >> 5;      // 0..1
    const int c4   = lane & 31;

    f32x4 acc[8];
    #pragma unroll
    for (int n = 0; n < 8; ++n)
        acc[n] = (f32x4){0.f, 0.f, 0.f, 0.f};

    const size_t rowBase = (size_t)bz*NDIM*MDIM + (size_t)(by*64 + w*16)*MDIM + (size_t)(bx*128);

    // ---- z prefetch: ENTIRE tile (largest HBM read, consumed last).
    //      epilogue element (rr,i) -> row = i*4 + rr*2 + hi, col4 = c4 ----
    int4 zpre[8];
    #pragma unroll
    for (int rr = 0; rr < 2; ++rr)
        #pragma unroll
        for (int i = 0; i < 4; ++i)
            zpre[rr*4+i] = *(const int4*)(zp + rowBase + (size_t)(i*4 + rr*2 + hi)*MDIM + c4*4);

    // ---- stage ALL of B (source-swizzled, linear LDS dest): 8 chunks/thread ----
    #pragma unroll
    for (int i = 0; i < 8; ++i){
        int chunk = i*256 + t;
        int row = chunk >> 4, pp = chunk & 15;
        int srcpos = pp ^ (row & 7);
        gload_lds16(x2b + ((size_t)(x2r0 + row))*128 + srcpos*8,
                    lB + (size_t)(i*256 + w*64)*8);
    }
    __syncthreads();

    // ---- MFMA: 4 k-steps of 32, A direct from global (L3-hot) ----
    const unsigned short* aRow = x1b + ((size_t)(bz*NDIM + by*64 + w*16 + l16))*128 + quad*8;
    #pragma unroll
    for (int kk = 0; kk < 4; ++kk){
        bf16x8 afr = *(const bf16x8*)(aRow + kk*32);
        const int kc = kk*4 + quad;              // 16B k-chunk 0..15
        #pragma unroll
        for (int g2 = 0; g2 < 2; ++g2){
            bf16x8 bfr[4];
            #pragma unroll
            for (int nn = 0; nn < 4; ++nn){
                int brow = (g2*4 + nn)*16 + l16;
                bfr[nn] = ((const bf16x8*)lB)[brow*16 + (kc ^ (brow & 7))];
            }
            #pragma unroll
            for (int nn = 0; nn < 4; ++nn)
                acc[g2*4+nn] = __builtin_amdgcn_mfma_f32_16x16x32_bf16(
                                afr, bfr[nn], acc[g2*4+nn], 0, 0, 0);
        }
    }

    // norms after MFMA (L2/L3-hot; keeps MFMA-window reg pressure low)
    float in1[4], in2[8];
    #pragma unroll
    for (int r = 0; r < 4; ++r) in1[r] = inv[bz*NDIM + by*64 + w*16 + quad*4 + r];
    #pragma unroll
    for (int n = 0; n < 8; ++n) in2[n] = inv[16384 + x2r0 + n*16 + l16];

    __syncthreads();   // B reads done -> per-wave scratch overlay safe

    // ---- barrier-free epilogue: per-wave 8x128 transpose scratch, 2 rounds ----
    float* scr = (float*)lB + w*1024;        // [8][128] f32, col-rotated by sr*4
    float* cosOut  = out + 1;
    float* maskOut = out + 1 + (size_t)BATCH*NDIM*MDIM;

    float lnum = 0.f;
    int   lcnt = 0;

    #pragma unroll
    for (int rr = 0; rr < 2; ++rr){
        // scatter: rows quad*4 + rr*2 + j -> scr row sr = quad*2+j
        #pragma unroll
        for (int n = 0; n < 8; ++n){
            #pragma unroll
            for (int j = 0; j < 2; ++j){
                int r  = rr*2 + j;
                int sr = quad*2 + j;
                scr[sr*128 + ((n*16 + l16 + sr*4) & 127)] = acc[n][r] * in1[r] * in2[n];
            }
        }
        // gather + math + streaming stores (wave-local LDS dep -> lgkmcnt only)
        #pragma unroll
        for (int i = 0; i < 4; ++i){
            int sr  = i*2 + hi;
            int col = (c4*4 + sr*4) & 127;
            f32x4 cs4 = *(const f32x4*)(scr + sr*128 + col);
            int rowRel = i*4 + rr*2 + hi;
            size_t idx = rowBase + (size_t)rowRel*MDIM + c4*4;

            int4 z4 = zpre[rr*4+i];
            f32x4 mk;
            float nl = 0.f;
            int   nc = 0;
            #pragma unroll
            for (int j = 0; j < 4; ++j){
                int zv = (&z4.x)[j];
                float cs = cs4[j];
                mk[j] = zv ? 1.0f : 0.0f;
                float y2  = (float)zv * (t2*cs - b2);
                float nll = fmaxf(-y2, 0.f) + log2f(1.0f + exp2f(-fabsf(y2)));
                nl += zv ? nll : 0.f;
                nc += zv ? 1 : 0;
            }
            lnum += nl;
            lcnt += nc;
            *(f32x4u*)(cosOut  + idx) = cs4;
            *(f32x4u*)(maskOut + idx) = mk;
        }
    }
    lnum *= 0.69314718f;   // back from log2 domain

    // ---- block-level loss reduction: 1 atomic pair per block ----
    #pragma unroll
    for (int off = 32; off > 0; off >>= 1){
        lnum += __shfl_down(lnum, off);
        lcnt += __shfl_down(lcnt, off);
    }
    __syncthreads();                 // scratch reads done; reuse for reduce
    float* redf = (float*)lB;
    int*   redi = (int*)lB + 8;
    if (lane == 0){ redf[w] = lnum; redi[w] = lcnt; }
    __syncthreads();
    if (t == 0){
        float s = redf[0] + redf[1] + redf[2] + redf[3];
        int   c = redi[0] + redi[1] + redi[2] + redi[3];
        int cell = (bx + by*16 + bz*512) & 31;
        atomicAdd(cells + cell, s);
        atomicAdd((int*)cells + 32 + cell, c);
    }
}

// ---------------- fallback (proven R6 kernel, used if ws too small) ----------------
__global__ void ws_init_kernel(unsigned int* cells){
    cells[threadIdx.x] = 0u;
}

__global__ __launch_bounds__(256, 5) void cossim_bce_main(
    const int*  __restrict__ zp,
    const float* __restrict__ x1,
    const float* __restrict__ x2,
    const float* __restrict__ tparm,
    const float* __restrict__ bparm,
    float* __restrict__ out,
    float* __restrict__ wsf)
{
    __shared__ __align__(16) unsigned short lds[(64 + 128) * 64];
    __shared__ float nsh[192];
    unsigned short* lA = lds;
    unsigned short* lB = lds + 64*64;

    const int t  = threadIdx.x;
    const int bx = blockIdx.x;
    const int by = blockIdx.y;
    const int bz = blockIdx.z;

    const float tv = *tparm;
    const float bv = *bparm;

    const float* x1base = x1 + ((size_t)(bz*NDIM) + by*64 ) * CDIM;
    const float* x2base = x2 + ((size_t)(bz*MDIM) + bx*128) * CDIM;

    const int lane = t & 63;
    const int w    = t >> 6;
    const int quad = lane >> 4;
    const int l16  = lane & 15;
    const int hi   = lane >> 5;
    const int c4   = lane & 31;

    f32x4 acc[8];
    #pragma unroll
    for (int n = 0; n < 8; ++n)
        acc[n] = (f32x4){0.f, 0.f, 0.f, 0.f};

    float nsum = 0.f;

    #pragma unroll
    for (int ph = 0; ph < 2; ++ph){
        #pragma unroll
        for (int i = 0; i < 6; ++i){
            int chunk = i*256 + t;
            const float* srcb;
            uint4* dst;
            int row, pos;
            if (i < 2){
                row = chunk >> 3; pos = chunk & 7;
                srcb = x1base; dst = (uint4*)lA;
            } else {
                int c2 = chunk - 512;
                row = c2 >> 3; pos = c2 & 7;
                srcb = x2base; dst = (uint4*)lB;
            }
            const float* p = srcb + row*CDIM + ph*64 + pos*8;
            float4 a = *(const float4*)p;
            float4 b = *(const float4*)(p + 4);
            uint4 pk;
            pk.x = f2bf(a.x) | (f2bf(a.y) << 16);
            pk.y = f2bf(a.z) | (f2bf(a.w) << 16);
            pk.z = f2bf(b.x) | (f2bf(b.y) << 16);
            pk.w = f2bf(b.z) | (f2bf(b.w) << 16);
            dst[row*8 + (pos ^ (row & 7))] = pk;
        }
        __syncthreads();

        #pragma unroll
        for (int kk = 0; kk < 2; ++kk){
            const int kc = kk*4 + quad;
            const int arow = w*16 + l16;
            bf16x8 afr = ((const bf16x8*)lA)[arow*8 + (kc ^ (arow & 7))];
            #pragma unroll
            for (int g = 0; g < 2; ++g){
                bf16x8 bfr[4];
                #pragma unroll
                for (int nn = 0; nn < 4; ++nn){
                    int brow = (g*4 + nn)*16 + l16;
                    bfr[nn] = ((const bf16x8*)lB)[brow*8 + (kc ^ (brow & 7))];
                }
                #pragma unroll
                for (int nn = 0; nn < 4; ++nn)
                    acc[g*4+nn] = __builtin_amdgcn_mfma_f32_16x16x32_bf16(
                                    afr, bfr[nn], acc[g*4+nn], 0, 0, 0);
            }
        }

        if (t < 192){
            const uint4* base; int row;
            if (t < 64){ base = (const uint4*)lA; row = t; }
            else       { base = (const uint4*)lB; row = t - 64; }
            #pragma unroll
            for (int c = 0; c < 8; ++c){
                uint4 v = base[row*8 + (c ^ (row & 7))];
                float f0 = bf2f(v.x & 0xffffu), f1 = bf2f(v.x >> 16);
                float f2 = bf2f(v.y & 0xffffu), f3 = bf2f(v.y >> 16);
                float f4 = bf2f(v.z & 0xffffu), f5 = bf2f(v.z >> 16);
                float f6 = bf2f(v.w & 0xffffu), f7 = bf2f(v.w >> 16);
                nsum += f0*f0 + f1*f1 + f2*f2 + f3*f3 + f4*f4 + f5*f5 + f6*f6 + f7*f7;
            }
        }
        __syncthreads();
    }

    if (t < 192) nsh[t] = 1.0f / sqrtf(fmaxf(nsum, 1e-16f));
    __syncthreads();

    float in1[4], in2[8];
    #pragma unroll
    for (int r = 0; r < 4; ++r) in1[r] = nsh[w*16 + quad*4 + r];
    #pragma unroll
    for (int n = 0; n < 8; ++n) in2[n] = nsh[64 + n*16 + l16];

    float* scr = (float*)lds + w*1024;
    float* cosOut  = out + 1;
    float* maskOut = out + 1 + (size_t)BATCH*NDIM*MDIM;
    const size_t rowBase = (size_t)bz*NDIM*MDIM + (size_t)(by*64 + w*16)*MDIM + (size_t)(bx*128);

    float lnum = 0.f;
    int   lcnt = 0;

    int4 zpre[4];
    #pragma unroll
    for (int i = 0; i < 4; ++i)
        zpre[i] = *(const int4*)(zp + rowBase + (size_t)(i*4 + hi)*MDIM + c4*4);

    #pragma unroll
    for (int rr = 0; rr < 2; ++rr){
        #pragma unroll
        for (int n = 0; n < 8; ++n){
            #pragma unroll
            for (int j = 0; j < 2; ++j){
                int r  = rr*2 + j;
                int sr = quad*2 + j;
                scr[sr*128 + ((n*16 + l16 + sr*4) & 127)] = acc[n][r] * in1[r] * in2[n];
            }
        }
        #pragma unroll
        for (int i = 0; i < 4; ++i){
            int sr  = i*2 + hi;
            int col = (c4*4 + sr*4) & 127;
            f32x4 cs4 = *(const f32x4*)(scr + sr*128 + col);
            int rowRel = i*4 + rr*2 + hi;
            size_t idx = rowBase + (size_t)rowRel*MDIM + c4*4;

            int4 z4 = zpre[i];
            if (rr == 0)
                zpre[i] = *(const int4*)(zp + idx + (size_t)2*MDIM);

            f32x4 mk;
            float nl = 0.f;
            int   nc = 0;
            #pragma unroll
            for (int j = 0; j < 4; ++j){
                int zv = (&z4.x)[j];
                float cs = cs4[j];
                mk[j] = zv ? 1.0f : 0.0f;
                float y  = (float)zv * (tv*cs - bv);
                float nll = fmaxf(-y, 0.f) + __logf(1.0f + __expf(-fabsf(y)));
                nl += zv ? nll : 0.f;
                nc += zv ? 1 : 0;
            }
            lnum += nl;
            lcnt += nc;
            *(f32x4u*)(cosOut  + idx) = cs4;
            *(f32x4u*)(maskOut + idx) = mk;
        }
    }

    #pragma unroll
    for (int off = 32; off > 0; off >>= 1){
        lnum += __shfl_down(lnum, off);
        lcnt += __shfl_down(lcnt, off);
    }
    __syncthreads();
    if (lane == 0){ nsh[w] = lnum; ((int*)nsh)[4 + w] = lcnt; }
    __syncthreads();
    if (t == 0){
        float s = nsh[0] + nsh[1] + nsh[2] + nsh[3];
        int   c = ((int*)nsh)[4] + ((int*)nsh)[5] + ((int*)nsh)[6] + ((int*)nsh)[7];
        int cell = (bx + by*16 + bz*512) & 31;
        atomicAdd(wsf + cell, s);
        atomicAdd((int*)wsf + 32 + cell, c);
    }
}

extern "C" void kernel_launch(void* const* d_in, const int* in_sizes, int n_in,
                              void* d_out, int out_size, void* d_ws, size_t ws_size,
                              hipStream_t stream) {
    const int*   zp = (const int*)  d_in[0];
    const float* x1 = (const float*)d_in[1];
    const float* x2 = (const float*)d_in[2];
    const float* tp = (const float*)d_in[3];
    const float* bp = (const float*)d_in[4];
    float* out = (float*)d_out;

    // ws fast-path layout: xb bf16[32768*128] (8 MB) | inv f32[32768] (128 KB) | cells (256 B)
    const size_t WS_NEEDED = (size_t)8*1024*1024 + 32768*4 + 256;
    dim3 grid(MDIM/128, NDIM/64, BATCH);

    if (ws_size >= WS_NEEDED){
        unsigned short* xb  = (unsigned short*)d_ws;
        float* inv   = (float*)((char*)d_ws + (size_t)8*1024*1024);
        float* cells = inv + 32768;
        prep_kernel<<<2048, 256, 0, stream>>>(x1, x2, xb, inv, (unsigned int*)cells);
        cossim_bce_fast<<<grid, 256, 0, stream>>>(zp, xb, inv, tp, bp, out, cells);
        finalize_kernel<<<1, 1, 0, stream>>>(cells, out);
    } else {
        float* wsf = (float*)d_ws;
        ws_init_kernel<<<1, 64, 0, stream>>>((unsigned int*)d_ws);
        cossim_bce_main<<<grid, 256, 0, stream>>>(zp, x1, x2, tp, bp, out, wsf);
        finalize_kernel<<<1, 1, 0, stream>>>(wsf, out);
    }
}

// Round 13
// 116.828 us; speedup vs baseline: 1.0958x; 1.0958x over previous
//
#include <hip/hip_runtime.h>
#include <hip/hip_bf16.h>

#define BATCH 8
#define NDIM  2048
#define MDIM  2048
#define CDIM  128

typedef __attribute__((ext_vector_type(8))) short bf16x8;
typedef __attribute__((ext_vector_type(4))) float f32x4;
// 4B-aligned float4 for the (out+1)-offset misaligned global stores
typedef __attribute__((ext_vector_type(4), aligned(4))) float f32x4u;

__device__ __forceinline__ float bf2f(unsigned int u16){
    union { unsigned int u; float f; } v; v.u = u16 << 16; return v.f;
}
__device__ __forceinline__ unsigned int f2bf(float f){
    union { float f; unsigned int u; } v; v.f = f;
    unsigned int u = v.u;
    u += 0x7FFFu + ((u >> 16) & 1u);   // round-to-nearest-even
    return u >> 16;
}

__device__ __forceinline__ void gload_lds16(const void* g, void* l){
    __builtin_amdgcn_global_load_lds(
        (const __attribute__((address_space(1))) void*)g,
        (__attribute__((address_space(3))) void*)l, 16, 0, 0);
}

__global__ void finalize_kernel(const float* cells, float* out){
    float s = 0.f;
    int   c = 0;
    #pragma unroll
    for (int i = 0; i < 32; ++i){
        s += cells[i];
        c += ((const int*)cells)[32 + i];
    }
    out[0] = s / (float)c;
}

// ---------------- pre-pass: f32 -> bf16 + per-row 1/||row|| + cells zero ----------------
__global__ __launch_bounds__(256) void prep_kernel(
    const float* __restrict__ x1, const float* __restrict__ x2,
    unsigned short* __restrict__ xb, float* __restrict__ inv,
    unsigned int* __restrict__ cells)
{
    if (blockIdx.x == 0 && threadIdx.x < 64) cells[threadIdx.x] = 0u;

    int gt  = blockIdx.x*256 + threadIdx.x;   // 0..524287
    int row = gt >> 4;                        // 0..32767
    int seg = gt & 15;                        // 8-elem segment
    const float* src = (row < 16384) ? (x1 + (size_t)row*128)
                                     : (x2 + (size_t)(row - 16384)*128);
    float4 a = *(const float4*)(src + seg*8);
    float4 b = *(const float4*)(src + seg*8 + 4);
    uint4 pk;
    pk.x = f2bf(a.x) | (f2bf(a.y) << 16);
    pk.y = f2bf(a.z) | (f2bf(a.w) << 16);
    pk.z = f2bf(b.x) | (f2bf(b.y) << 16);
    pk.w = f2bf(b.z) | (f2bf(b.w) << 16);
    ((uint4*)xb)[(size_t)row*16 + seg] = pk;

    float f0 = bf2f(pk.x & 0xffffu), f1 = bf2f(pk.x >> 16);
    float f2 = bf2f(pk.y & 0xffffu), f3 = bf2f(pk.y >> 16);
    float f4 = bf2f(pk.z & 0xffffu), f5 = bf2f(pk.z >> 16);
    float f6 = bf2f(pk.w & 0xffffu), f7 = bf2f(pk.w >> 16);
    float s = f0*f0 + f1*f1 + f2*f2 + f3*f3 + f4*f4 + f5*f5 + f6*f6 + f7*f7;
    s += __shfl_xor(s, 1);
    s += __shfl_xor(s, 2);
    s += __shfl_xor(s, 4);
    s += __shfl_xor(s, 8);
    if (seg == 0) inv[row] = 1.0f / sqrtf(fmaxf(s, 1e-16f));
}

// ---------------- main: EXACT R8 structure (118.6us proven) + exp2 softplus ----------------
// Tile 64(N) x 128(M); 256 thr / 4 waves; wave owns 16 rows x 128 cols (acc = 32 AGPR).
// B tile [128][128] bf16 (32 KB) staged in ONE global_load_lds round, XOR-swizzle
// folded into the global SOURCE address; z round-0 prefetched before staging,
// round-1 z issued inside epilogue round 0 (zpre[4]=16 VGPR; zpre[8] SPILLED, R12).
// launch_bounds(256,5): 102-reg cap; peak ~96 (64 V + 32 A).
__global__ __launch_bounds__(256, 5) void cossim_bce_fast(
    const int*  __restrict__ zp,
    const unsigned short* __restrict__ xb,
    const float* __restrict__ inv,
    const float* __restrict__ tparm,
    const float* __restrict__ bparm,
    float* __restrict__ out,
    float* __restrict__ cells)
{
    __shared__ __align__(16) unsigned short lB[128*128];   // 32 KB; scratch overlay

    const int t  = threadIdx.x;
    const int bx = blockIdx.x;   // M tile 0..15
    const int by = blockIdx.y;   // N tile 0..31
    const int bz = blockIdx.z;   // batch

    // exp2-domain softplus: y2 = z*(t2*cs - b2); nll = ln2 * softplus2(-y2)
    const float t2 = *tparm * 1.44269504f;
    const float b2 = *bparm * 1.44269504f;

    const unsigned short* x1b = xb;                          // 16384 x 128
    const unsigned short* x2b = xb + (size_t)16384*128;      // 16384 x 128
    const int x2r0 = bz*MDIM + bx*128;

    const int lane = t & 63;
    const int w    = t >> 6;
    const int quad = lane >> 4;      // 0..3
    const int l16  = lane & 15;
    const int hi   = lane >> 5;      // 0..1
    const int c4   = lane & 31;

    f32x4 acc[8];
    #pragma unroll
    for (int n = 0; n < 8; ++n)
        acc[n] = (f32x4){0.f, 0.f, 0.f, 0.f};

    const size_t rowBase = (size_t)bz*NDIM*MDIM + (size_t)(by*64 + w*16)*MDIM + (size_t)(bx*128);

    // ---- z prefetch FIRST (round 0: rows i*4 + hi) ----
    int4 zpre[4];
    #pragma unroll
    for (int i = 0; i < 4; ++i)
        zpre[i] = *(const int4*)(zp + rowBase + (size_t)(i*4 + hi)*MDIM + c4*4);

    // ---- stage ALL of B (source-swizzled, linear LDS dest): 8 chunks/thread ----
    #pragma unroll
    for (int i = 0; i < 8; ++i){
        int chunk = i*256 + t;
        int row = chunk >> 4, pp = chunk & 15;
        int srcpos = pp ^ (row & 7);
        gload_lds16(x2b + ((size_t)(x2r0 + row))*128 + srcpos*8,
                    lB + (size_t)(i*256 + w*64)*8);
    }
    __syncthreads();

    // ---- MFMA: 4 k-steps of 32, A direct from global (L3-hot) ----
    const unsigned short* aRow = x1b + ((size_t)(bz*NDIM + by*64 + w*16 + l16))*128 + quad*8;
    #pragma unroll
    for (int kk = 0; kk < 4; ++kk){
        bf16x8 afr = *(const bf16x8*)(aRow + kk*32);
        const int kc = kk*4 + quad;              // 16B k-chunk 0..15
        #pragma unroll
        for (int g2 = 0; g2 < 2; ++g2){
            bf16x8 bfr[4];
            #pragma unroll
            for (int nn = 0; nn < 4; ++nn){
                int brow = (g2*4 + nn)*16 + l16;
                bfr[nn] = ((const bf16x8*)lB)[brow*16 + (kc ^ (brow & 7))];
            }
            #pragma unroll
            for (int nn = 0; nn < 4; ++nn)
                acc[g2*4+nn] = __builtin_amdgcn_mfma_f32_16x16x32_bf16(
                                afr, bfr[nn], acc[g2*4+nn], 0, 0, 0);
        }
    }

    // norms after MFMA (L2/L3-hot; keeps MFMA-window reg pressure low)
    float in1[4], in2[8];
    #pragma unroll
    for (int r = 0; r < 4; ++r) in1[r] = inv[bz*NDIM + by*64 + w*16 + quad*4 + r];
    #pragma unroll
    for (int n = 0; n < 8; ++n) in2[n] = inv[16384 + x2r0 + n*16 + l16];

    __syncthreads();   // B reads done -> per-wave scratch overlay safe

    // ---- barrier-free epilogue: per-wave 8x128 transpose scratch, 2 rounds ----
    float* scr = (float*)lB + w*1024;        // [8][128] f32, col-rotated by sr*4
    float* cosOut  = out + 1;
    float* maskOut = out + 1 + (size_t)BATCH*NDIM*MDIM;

    float lnum = 0.f;
    int   lcnt = 0;

    #pragma unroll
    for (int rr = 0; rr < 2; ++rr){
        // scatter: rows quad*4 + rr*2 + j -> scr row sr = quad*2+j
        #pragma unroll
        for (int n = 0; n < 8; ++n){
            #pragma unroll
            for (int j = 0; j < 2; ++j){
                int r  = rr*2 + j;
                int sr = quad*2 + j;
                scr[sr*128 + ((n*16 + l16 + sr*4) & 127)] = acc[n][r] * in1[r] * in2[n];
            }
        }
        // gather + math + streaming stores (wave-local LDS dep -> lgkmcnt only)
        #pragma unroll
        for (int i = 0; i < 4; ++i){
            int sr  = i*2 + hi;
            int col = (c4*4 + sr*4) & 127;
            f32x4 cs4 = *(const f32x4*)(scr + sr*128 + col);
            int rowRel = i*4 + rr*2 + hi;
            size_t idx = rowBase + (size_t)rowRel*MDIM + c4*4;

            int4 z4 = zpre[i];
            if (rr == 0)   // issue round-1 z load now (rows +2)
                zpre[i] = *(const int4*)(zp + idx + (size_t)2*MDIM);

            f32x4 mk;
            float nl = 0.f;
            int   nc = 0;
            #pragma unroll
            for (int j = 0; j < 4; ++j){
                int zv = (&z4.x)[j];
                float cs = cs4[j];
                mk[j] = zv ? 1.0f : 0.0f;
                float y2  = (float)zv * (t2*cs - b2);
                float nll = fmaxf(-y2, 0.f) + log2f(1.0f + exp2f(-fabsf(y2)));
                nl += zv ? nll : 0.f;
                nc += zv ? 1 : 0;
            }
            lnum += nl;
            lcnt += nc;
            *(f32x4u*)(cosOut  + idx) = cs4;
            *(f32x4u*)(maskOut + idx) = mk;
        }
    }
    lnum *= 0.69314718f;   // back from log2 domain

    // ---- block-level loss reduction: 1 atomic pair per block ----
    #pragma unroll
    for (int off = 32; off > 0; off >>= 1){
        lnum += __shfl_down(lnum, off);
        lcnt += __shfl_down(lcnt, off);
    }
    __syncthreads();                 // scratch reads done; reuse for reduce
    float* redf = (float*)lB;
    int*   redi = (int*)lB + 8;
    if (lane == 0){ redf[w] = lnum; redi[w] = lcnt; }
    __syncthreads();
    if (t == 0){
        float s = redf[0] + redf[1] + redf[2] + redf[3];
        int   c = redi[0] + redi[1] + redi[2] + redi[3];
        int cell = (bx + by*16 + bz*512) & 31;
        atomicAdd(cells + cell, s);
        atomicAdd((int*)cells + 32 + cell, c);
    }
}

// ---------------- fallback (proven R6 kernel, used if ws too small) ----------------
__global__ void ws_init_kernel(unsigned int* cells){
    cells[threadIdx.x] = 0u;
}

__global__ __launch_bounds__(256, 5) void cossim_bce_main(
    const int*  __restrict__ zp,
    const float* __restrict__ x1,
    const float* __restrict__ x2,
    const float* __restrict__ tparm,
    const float* __restrict__ bparm,
    float* __restrict__ out,
    float* __restrict__ wsf)
{
    __shared__ __align__(16) unsigned short lds[(64 + 128) * 64];
    __shared__ float nsh[192];
    unsigned short* lA = lds;
    unsigned short* lB = lds + 64*64;

    const int t  = threadIdx.x;
    const int bx = blockIdx.x;
    const int by = blockIdx.y;
    const int bz = blockIdx.z;

    const float tv = *tparm;
    const float bv = *bparm;

    const float* x1base = x1 + ((size_t)(bz*NDIM) + by*64 ) * CDIM;
    const float* x2base = x2 + ((size_t)(bz*MDIM) + bx*128) * CDIM;

    const int lane = t & 63;
    const int w    = t >> 6;
    const int quad = lane >> 4;
    const int l16  = lane & 15;
    const int hi   = lane >> 5;
    const int c4   = lane & 31;

    f32x4 acc[8];
    #pragma unroll
    for (int n = 0; n < 8; ++n)
        acc[n] = (f32x4){0.f, 0.f, 0.f, 0.f};

    float nsum = 0.f;

    #pragma unroll
    for (int ph = 0; ph < 2; ++ph){
        #pragma unroll
        for (int i = 0; i < 6; ++i){
            int chunk = i*256 + t;
            const float* srcb;
            uint4* dst;
            int row, pos;
            if (i < 2){
                row = chunk >> 3; pos = chunk & 7;
                srcb = x1base; dst = (uint4*)lA;
            } else {
                int c2 = chunk - 512;
                row = c2 >> 3; pos = c2 & 7;
                srcb = x2base; dst = (uint4*)lB;
            }
            const float* p = srcb + row*CDIM + ph*64 + pos*8;
            float4 a = *(const float4*)p;
            float4 b = *(const float4*)(p + 4);
            uint4 pk;
            pk.x = f2bf(a.x) | (f2bf(a.y) << 16);
            pk.y = f2bf(a.z) | (f2bf(a.w) << 16);
            pk.z = f2bf(b.x) | (f2bf(b.y) << 16);
            pk.w = f2bf(b.z) | (f2bf(b.w) << 16);
            dst[row*8 + (pos ^ (row & 7))] = pk;
        }
        __syncthreads();

        #pragma unroll
        for (int kk = 0; kk < 2; ++kk){
            const int kc = kk*4 + quad;
            const int arow = w*16 + l16;
            bf16x8 afr = ((const bf16x8*)lA)[arow*8 + (kc ^ (arow & 7))];
            #pragma unroll
            for (int g = 0; g < 2; ++g){
                bf16x8 bfr[4];
                #pragma unroll
                for (int nn = 0; nn < 4; ++nn){
                    int brow = (g*4 + nn)*16 + l16;
                    bfr[nn] = ((const bf16x8*)lB)[brow*8 + (kc ^ (brow & 7))];
                }
                #pragma unroll
                for (int nn = 0; nn < 4; ++nn)
                    acc[g*4+nn] = __builtin_amdgcn_mfma_f32_16x16x32_bf16(
                                    afr, bfr[nn], acc[g*4+nn], 0, 0, 0);
            }
        }

        if (t < 192){
            const uint4* base; int row;
            if (t < 64){ base = (const uint4*)lA; row = t; }
            else       { base = (const uint4*)lB; row = t - 64; }
            #pragma unroll
            for (int c = 0; c < 8; ++c){
                uint4 v = base[row*8 + (c ^ (row & 7))];
                float f0 = bf2f(v.x & 0xffffu), f1 = bf2f(v.x >> 16);
                float f2 = bf2f(v.y & 0xffffu), f3 = bf2f(v.y >> 16);
                float f4 = bf2f(v.z & 0xffffu), f5 = bf2f(v.z >> 16);
                float f6 = bf2f(v.w & 0xffffu), f7 = bf2f(v.w >> 16);
                nsum += f0*f0 + f1*f1 + f2*f2 + f3*f3 + f4*f4 + f5*f5 + f6*f6 + f7*f7;
            }
        }
        __syncthreads();
    }

    if (t < 192) nsh[t] = 1.0f / sqrtf(fmaxf(nsum, 1e-16f));
    __syncthreads();

    float in1[4], in2[8];
    #pragma unroll
    for (int r = 0; r < 4; ++r) in1[r] = nsh[w*16 + quad*4 + r];
    #pragma unroll
    for (int n = 0; n < 8; ++n) in2[n] = nsh[64 + n*16 + l16];

    float* scr = (float*)lds + w*1024;
    float* cosOut  = out + 1;
    float* maskOut = out + 1 + (size_t)BATCH*NDIM*MDIM;
    const size_t rowBase = (size_t)bz*NDIM*MDIM + (size_t)(by*64 + w*16)*MDIM + (size_t)(bx*128);

    float lnum = 0.f;
    int   lcnt = 0;

    int4 zpre[4];
    #pragma unroll
    for (int i = 0; i < 4; ++i)
        zpre[i] = *(const int4*)(zp + rowBase + (size_t)(i*4 + hi)*MDIM + c4*4);

    #pragma unroll
    for (int rr = 0; rr < 2; ++rr){
        #pragma unroll
        for (int n = 0; n < 8; ++n){
            #pragma unroll
            for (int j = 0; j < 2; ++j){
                int r  = rr*2 + j;
                int sr = quad*2 + j;
                scr[sr*128 + ((n*16 + l16 + sr*4) & 127)] = acc[n][r] * in1[r] * in2[n];
            }
        }
        #pragma unroll
        for (int i = 0; i < 4; ++i){
            int sr  = i*2 + hi;
            int col = (c4*4 + sr*4) & 127;
            f32x4 cs4 = *(const f32x4*)(scr + sr*128 + col);
            int rowRel = i*4 + rr*2 + hi;
            size_t idx = rowBase + (size_t)rowRel*MDIM + c4*4;

            int4 z4 = zpre[i];
            if (rr == 0)
                zpre[i] = *(const int4*)(zp + idx + (size_t)2*MDIM);

            f32x4 mk;
            float nl = 0.f;
            int   nc = 0;
            #pragma unroll
            for (int j = 0; j < 4; ++j){
                int zv = (&z4.x)[j];
                float cs = cs4[j];
                mk[j] = zv ? 1.0f : 0.0f;
                float y  = (float)zv * (tv*cs - bv);
                float nll = fmaxf(-y, 0.f) + __logf(1.0f + __expf(-fabsf(y)));
                nl += zv ? nll : 0.f;
                nc += zv ? 1 : 0;
            }
            lnum += nl;
            lcnt += nc;
            *(f32x4u*)(cosOut  + idx) = cs4;
            *(f32x4u*)(maskOut + idx) = mk;
        }
    }

    #pragma unroll
    for (int off = 32; off > 0; off >>= 1){
        lnum += __shfl_down(lnum, off);
        lcnt += __shfl_down(lcnt, off);
    }
    __syncthreads();
    if (lane == 0){ nsh[w] = lnum; ((int*)nsh)[4 + w] = lcnt; }
    __syncthreads();
    if (t == 0){
        float s = nsh[0] + nsh[1] + nsh[2] + nsh[3];
        int   c = ((int*)nsh)[4] + ((int*)nsh)[5] + ((int*)nsh)[6] + ((int*)nsh)[7];
        int cell = (bx + by*16 + bz*512) & 31;
        atomicAdd(wsf + cell, s);
        atomicAdd((int*)wsf + 32 + cell, c);
    }
}

extern "C" void kernel_launch(void* const* d_in, const int* in_sizes, int n_in,
                              void* d_out, int out_size, void* d_ws, size_t ws_size,
                              hipStream_t stream) {
    const int*   zp = (const int*)  d_in[0];
    const float* x1 = (const float*)d_in[1];
    const float* x2 = (const float*)d_in[2];
    const float* tp = (const float*)d_in[3];
    const float* bp = (const float*)d_in[4];
    float* out = (float*)d_out;

    // ws fast-path layout: xb bf16[32768*128] (8 MB) | inv f32[32768] (128 KB) | cells (256 B)
    const size_t WS_NEEDED = (size_t)8*1024*1024 + 32768*4 + 256;
    dim3 grid(MDIM/128, NDIM/64, BATCH);

    if (ws_size >= WS_NEEDED){
        unsigned short* xb  = (unsigned short*)d_ws;
        float* inv   = (float*)((char*)d_ws + (size_t)8*1024*1024);
        float* cells = inv + 32768;
        prep_kernel<<<2048, 256, 0, stream>>>(x1, x2, xb, inv, (unsigned int*)cells);
        cossim_bce_fast<<<grid, 256, 0, stream>>>(zp, xb, inv, tp, bp, out, cells);
        finalize_kernel<<<1, 1, 0, stream>>>(cells, out);
    } else {
        float* wsf = (float*)d_ws;
        ws_init_kernel<<<1, 64, 0, stream>>>((unsigned int*)d_ws);
        cossim_bce_main<<<grid, 256, 0, stream>>>(zp, x1, x2, tp, bp, out, wsf);
        finalize_kernel<<<1, 1, 0, stream>>>(wsf, out);
    }
}